// Round 3
// baseline (86.305 us; speedup 1.0000x reference)
//
#include <hip/hip_runtime.h>
#include <math.h>

// RBF kernel matrix: cov[i][j] = exp(lv - 0.5*||(x_i - xx_j) * inv_scale||^2)
// Expanded form: exponent = h_i + c_j + sum_d x[i,d] * B[j,d]
//   w[d]    = inv_scale[d]^2
//   B[j,d]  = xx[j,d] * w[d]
//   c[j]    = lv - 0.5 * sum_d xx[j,d]^2 * w[d]
//   h_i     = -0.5 * sum_d x[i,d]^2 * w[d]
// Per output: 8 FMA + 1 add + 1 exp. Write-BW bound: 67 MB fp32 out
// (floor ~11 us @ 6.2 TB/s). Output is write-once -> non-temporal stores
// to bypass L2 allocation (67 MB stream vs 32 MB L2).

constexpr int D   = 8;   // feature dim (fixed by reference)
constexpr int TJ  = 4;   // columns per thread  -> one float4 nt-store
constexpr int TI  = 8;   // rows per block      -> amortize column precompute
constexpr int BLK = 256; // threads per block

typedef float f32x4 __attribute__((ext_vector_type(4)));

__global__ __launch_bounds__(BLK) void rbf_kernel(
    const float* __restrict__ x,         // [N, D]
    const float* __restrict__ xx,        // [M, D]
    const float* __restrict__ log_scale, // [D]
    const float* __restrict__ log_var,   // [1]
    float* __restrict__ out,             // [N, M]
    int N, int M)
{
    const int j0 = (blockIdx.x * BLK + threadIdx.x) * TJ;
    const int i0 = blockIdx.y * TI;
    if (j0 + TJ > M || i0 + TI > N) return;  // exact grid for 4096; safety only

    float w[D];
#pragma unroll
    for (int d = 0; d < D; ++d) {
        const float s = __expf(-log_scale[d]);  // 1/scale
        w[d] = s * s;
    }
    const float lv = log_var[0];

    // Per-column precompute (registers): B[jj][d], c[jj]
    float B[TJ][D], c[TJ];
#pragma unroll
    for (int jj = 0; jj < TJ; ++jj) {
        const float4* p = (const float4*)(xx + (size_t)(j0 + jj) * D);
        const float4 a = p[0], b = p[1];
        const float v[D] = {a.x, a.y, a.z, a.w, b.x, b.y, b.z, b.w};
        float q = 0.f;
#pragma unroll
        for (int d = 0; d < D; ++d) {
            B[jj][d] = v[d] * w[d];
            q = fmaf(v[d], B[jj][d], q);       // sum xx^2 * w
        }
        c[jj] = fmaf(-0.5f, q, lv);
    }

#pragma unroll
    for (int r = 0; r < TI; ++r) {
        const int i = i0 + r;
        // x-row address is wave-uniform -> scalar/broadcast fetch, L1/L2-hot.
        const float4* px = (const float4*)(x + (size_t)i * D);
        const float4 a = px[0], b = px[1];
        const float v[D] = {a.x, a.y, a.z, a.w, b.x, b.y, b.z, b.w};
        float q = 0.f;
#pragma unroll
        for (int d = 0; d < D; ++d) q = fmaf(v[d] * w[d], v[d], q);
        const float h = -0.5f * q;

        float res[TJ];
#pragma unroll
        for (int jj = 0; jj < TJ; ++jj) {
            float e = h + c[jj];
#pragma unroll
            for (int d = 0; d < D; ++d) e = fmaf(v[d], B[jj][d], e);
            res[jj] = __expf(e);
        }
        const f32x4 o = {res[0], res[1], res[2], res[3]};
        // Write-once stream, never read back: non-temporal (nt) store
        // bypasses L2 allocation.
        __builtin_nontemporal_store(o, (f32x4*)(out + (size_t)i * M + j0));
    }
}

extern "C" void kernel_launch(void* const* d_in, const int* in_sizes, int n_in,
                              void* d_out, int out_size, void* d_ws, size_t ws_size,
                              hipStream_t stream) {
    const float* x  = (const float*)d_in[0];
    const float* xx = (const float*)d_in[1];
    const float* ls = (const float*)d_in[2];
    const float* lv = (const float*)d_in[3];
    float* out      = (float*)d_out;

    const int N = in_sizes[0] / D;
    const int M = in_sizes[1] / D;

    dim3 block(BLK, 1, 1);
    dim3 grid((M + BLK * TJ - 1) / (BLK * TJ), (N + TI - 1) / TI, 1);
    rbf_kernel<<<grid, block, 0, stream>>>(x, xx, ls, lv, out, N, M);
}